// Round 1
// baseline (87.217 us; speedup 1.0000x reference)
//
#include <hip/hip_runtime.h>
#include <hip/hip_bf16.h>

typedef __attribute__((ext_vector_type(8))) short short8;
typedef __attribute__((ext_vector_type(4))) float f32x4;

#define B_SZ 64
#define T_SZ 8192
#define D_SZ 128
#define U_SZ 128
#define T_TILE 128
#define N_TILES (T_SZ / T_TILE)   /* 64 tiles per batch */
#define P_STRIDE 132              /* c[128] + m + s, padded */

__device__ __forceinline__ unsigned short f2bf(float f) {
  // round-to-nearest-even fp32 -> bf16
  unsigned int u = __builtin_bit_cast(unsigned int, f);
  u += 0x7fffu + ((u >> 16) & 1u);
  return (unsigned short)(u >> 16);
}

__device__ __forceinline__ float fast_tanh(float x) {
  // tanh(x) = 1 - 2/(e^{2x}+1); saturates correctly at +-inf
  float e = __expf(2.0f * x);
  return 1.0f - 2.0f * __builtin_amdgcn_rcpf(e + 1.0f);
}

// ---------------------------------------------------------------------------
// Kernel 0: W [d][u] fp32 -> Wt [u][d] bf16 in workspace (done once, tiny)
// ---------------------------------------------------------------------------
__global__ void k_prep(const float* __restrict__ wk, unsigned short* __restrict__ wt) {
  int i = blockIdx.x * 256 + threadIdx.x;     // 16384 elements
  if (i < D_SZ * U_SZ) {
    int d = i >> 7, u = i & 127;
    wt[u * D_SZ + d] = f2bf(wk[i]);
  }
}

// ---------------------------------------------------------------------------
// Kernel 1: per (b, T-tile of 128): logits via bf16 MFMA, tile softmax
// partials (m, s) and partial weighted context c[128] -> pbuf
// ---------------------------------------------------------------------------
__global__ __launch_bounds__(256) void k_partial(
    const float* __restrict__ x, const unsigned short* __restrict__ wt_g,
    const float* __restrict__ wb, const float* __restrict__ v,
    const float* __restrict__ vb, float* __restrict__ pbuf)
{
  __shared__ unsigned short wt[U_SZ][136];  // +8 bf16 pad: 272B row stride
  __shared__ float wb_s[U_SZ], v_s[U_SZ];
  __shared__ float logits[T_TILE];
  __shared__ float pw[T_TILE];
  __shared__ float msum[2];
  __shared__ float cbuf[D_SZ];

  const int tid  = threadIdx.x;
  const int bidx = blockIdx.x;
  const int b    = bidx >> 6;       // /N_TILES
  const int tile = bidx & 63;

  // stage Wt (bf16, already [u][d]) into padded LDS; 16B chunks, coalesced
  for (int i = tid; i < U_SZ * 16; i += 256) {
    int row = i >> 4, c16 = i & 15;
    uint4 val = ((const uint4*)wt_g)[i];
    *(uint4*)&wt[row][c16 * 8] = val;
  }
  if (tid < U_SZ) { wb_s[tid] = wb[tid]; v_s[tid] = v[tid]; }
  __syncthreads();

  const int w  = tid >> 6;          // wave 0..3, owns rows w*32..w*32+31
  const int l  = tid & 63;
  const int lr = l & 15;            // A-row / B-col / D-col lane index
  const int lh = l >> 4;            // 0..3 -> k-subchunk / D-row group
  const size_t xbase = ((size_t)b * T_SZ + (size_t)tile * T_TILE) * D_SZ;

  // A fragments: 2 row-subtiles x 4 k-tiles, loaded straight from global fp32
  short8 afrag[2][4];
#pragma unroll
  for (int s = 0; s < 2; ++s) {
    const float* xr = x + xbase + (size_t)(w * 32 + s * 16 + lr) * D_SZ;
#pragma unroll
    for (int kt = 0; kt < 4; ++kt) {
      const float4 f0 = *(const float4*)(xr + kt * 32 + lh * 8);
      const float4 f1 = *(const float4*)(xr + kt * 32 + lh * 8 + 4);
      short8 a;
      a[0] = (short)f2bf(f0.x); a[1] = (short)f2bf(f0.y);
      a[2] = (short)f2bf(f0.z); a[3] = (short)f2bf(f0.w);
      a[4] = (short)f2bf(f1.x); a[5] = (short)f2bf(f1.y);
      a[6] = (short)f2bf(f1.z); a[7] = (short)f2bf(f1.w);
      afrag[s][kt] = a;
    }
  }

  // logit accumulators per lane (partial row-sums over this lane's u-column)
  float lg0[4] = {0.f, 0.f, 0.f, 0.f};
  float lg1[4] = {0.f, 0.f, 0.f, 0.f};

#pragma unroll
  for (int ut = 0; ut < 8; ++ut) {
    f32x4 acc0 = {0.f, 0.f, 0.f, 0.f};
    f32x4 acc1 = {0.f, 0.f, 0.f, 0.f};
#pragma unroll
    for (int kt = 0; kt < 4; ++kt) {
      short8 bfrag = *(const short8*)&wt[ut * 16 + lr][kt * 32 + lh * 8];
      acc0 = __builtin_amdgcn_mfma_f32_16x16x32_bf16(afrag[0][kt], bfrag, acc0, 0, 0, 0);
      acc1 = __builtin_amdgcn_mfma_f32_16x16x32_bf16(afrag[1][kt], bfrag, acc1, 0, 0, 0);
    }
    const float wbv = wb_s[ut * 16 + lr];
    const float vv  = v_s[ut * 16 + lr];
#pragma unroll
    for (int r = 0; r < 4; ++r) {
      lg0[r] += fast_tanh(acc0[r] + wbv) * vv;
      lg1[r] += fast_tanh(acc1[r] + wbv) * vv;
    }
  }

  // reduce over the 16 u-columns (lane bits 0..3)
#pragma unroll
  for (int m = 1; m <= 8; m <<= 1) {
#pragma unroll
    for (int r = 0; r < 4; ++r) {
      lg0[r] += __shfl_xor(lg0[r], m, 64);
      lg1[r] += __shfl_xor(lg1[r], m, 64);
    }
  }
  const float vbias = vb[0];
  if (lr == 0) {
#pragma unroll
    for (int r = 0; r < 4; ++r) {
      logits[w * 32 +      lh * 4 + r] = lg0[r] + vbias;
      logits[w * 32 + 16 + lh * 4 + r] = lg1[r] + vbias;
    }
  }
  __syncthreads();

  // tile softmax partials (wave 0)
  if (tid < 64) {
    float l0 = logits[tid], l1 = logits[64 + tid];
    float mx = fmaxf(l0, l1);
#pragma unroll
    for (int m = 1; m <= 32; m <<= 1) mx = fmaxf(mx, __shfl_xor(mx, m, 64));
    float p0 = __expf(l0 - mx), p1 = __expf(l1 - mx);
    float ss = p0 + p1;
#pragma unroll
    for (int m = 1; m <= 32; m <<= 1) ss += __shfl_xor(ss, m, 64);
    pw[tid] = p0; pw[64 + tid] = p1;
    if (tid == 0) { msum[0] = mx; msum[1] = ss; }
  }
  __syncthreads();

  // partial weighted context: c[d] = sum_t pw[t] * x[t][d]  (x re-read, L2-hot)
  const int d = tid & 127, g = tid >> 7;
  const float* xg = x + xbase + (size_t)g * 64 * D_SZ + d;
  float c = 0.0f;
#pragma unroll 8
  for (int t = 0; t < 64; ++t) c = fmaf(pw[g * 64 + t], xg[(size_t)t * D_SZ], c);
  if (g == 0) cbuf[d] = c;
  __syncthreads();
  if (g == 1) cbuf[d] += c;
  __syncthreads();

  float* pb = pbuf + (size_t)bidx * P_STRIDE;
  if (tid < 128)      pb[tid] = cbuf[tid];
  else if (tid == 128) pb[128] = msum[0];
  else if (tid == 129) pb[129] = msum[1];
}

// ---------------------------------------------------------------------------
// Kernel 2: combine 64 tile-partials per batch with global softmax rescale
// ---------------------------------------------------------------------------
__global__ __launch_bounds__(128) void k_combine(const float* __restrict__ pbuf,
                                                 float* __restrict__ out)
{
  const int b = blockIdx.x, tid = threadIdx.x;
  __shared__ float sc[N_TILES];
  __shared__ float stot_s;
  const float* pb = pbuf + (size_t)b * N_TILES * P_STRIDE;

  if (tid < 64) {
    float m = pb[tid * P_STRIDE + 128];
    float mx = m;
#pragma unroll
    for (int k = 1; k <= 32; k <<= 1) mx = fmaxf(mx, __shfl_xor(mx, k, 64));
    float e = __expf(m - mx);
    float s = pb[tid * P_STRIDE + 129] * e;
    float st = s;
#pragma unroll
    for (int k = 1; k <= 32; k <<= 1) st += __shfl_xor(st, k, 64);
    sc[tid] = e;
    if (tid == 0) stot_s = st;
  }
  __syncthreads();

  float c = 0.0f;
#pragma unroll 8
  for (int i = 0; i < N_TILES; ++i) c = fmaf(pb[(size_t)i * P_STRIDE + tid], sc[i], c);
  out[b * D_SZ + tid] = c / stot_s;
}

// ---------------------------------------------------------------------------
extern "C" void kernel_launch(void* const* d_in, const int* in_sizes, int n_in,
                              void* d_out, int out_size, void* d_ws, size_t ws_size,
                              hipStream_t stream) {
  const float* x  = (const float*)d_in[0];  // [B,T,D]
  const float* wk = (const float*)d_in[1];  // [D,U]
  const float* wb = (const float*)d_in[2];  // [U]
  const float* vk = (const float*)d_in[3];  // [U,1]
  const float* vb = (const float*)d_in[4];  // [1]
  float* out = (float*)d_out;               // [B,D]

  unsigned short* wt = (unsigned short*)d_ws;               // 32 KB bf16 Wt[u][d]
  float* pbuf = (float*)((char*)d_ws + 32768);              // 4096 * 132 floats

  k_prep<<<64, 256, 0, stream>>>(wk, wt);
  k_partial<<<B_SZ * N_TILES, 256, 0, stream>>>(x, wt, wb, vk, vb, pbuf);
  k_combine<<<B_SZ, 128, 0, stream>>>(pbuf, out);
}